// Round 5
// baseline (8265.488 us; speedup 1.0000x reference)
//
#include <hip/hip_runtime.h>
#include <cstdint>

#define T_LEN 2048
#define NB    32
#define NROWS (NB*T_LEN)   // 65536
#define HH    200
#define TB    256          // LSTM time-chunk (per dispatch)

typedef _Float16 f16;
typedef _Float16 f16x2 __attribute__((ext_vector_type(2)));
typedef _Float16 f16x4 __attribute__((ext_vector_type(4)));
typedef _Float16 f16x8 __attribute__((ext_vector_type(8)));
typedef float   floatx4 __attribute__((ext_vector_type(4)));

static __device__ __forceinline__ unsigned short f2h(float x) {
  f16 h = (f16)x; return __builtin_bit_cast(unsigned short, h);
}
static __device__ __forceinline__ float sigm(float x) {
  return __builtin_amdgcn_rcpf(1.f + __expf(-x));
}
static __device__ __forceinline__ float tanh_fast(float x) {
  return 1.f - 2.f * __builtin_amdgcn_rcpf(__expf(2.f * x) + 1.f);
}

// ---------------- P/Q precompute: P[dt,co]=sum_ci relu(k1)k2, Q with relu(-k1)
__global__ void pq_kernel(const float* __restrict__ k1w, const float* __restrict__ k2w,
                          float* __restrict__ PQ) {
  int id = blockIdx.x * 256 + threadIdx.x;   // 1536 total
  int pq = id / 768;
  int rem = id % 768;
  int wdt = rem / 256;
  int co  = rem % 256;
  float acc = 0.f;
  for (int ci = 0; ci < 256; ++ci) {
    float k = k1w[ci];
    float kk = pq ? fmaxf(-k, 0.f) : fmaxf(k, 0.f);
    acc += kk * k2w[((size_t)wdt * 256 + ci) * 256 + co];
  }
  PQ[id] = acc;
}

// ---------------- f16 weight prep
// K3T[co][ci] ; Wx2[dir][c][k] with permuted col c=4u+q (gate g=q*200+u) ;
// WhTp[dir][m<896][k<208], row m=4u+q -> Wh[k][q*200+u], zero-padded ; bcat permuted.
__global__ void prep_kernel(const float* __restrict__ k3w,
                            const float* __restrict__ Wf, const float* __restrict__ bfv,
                            const float* __restrict__ Wb, const float* __restrict__ bbv,
                            unsigned short* __restrict__ K3h, unsigned short* __restrict__ Wx2,
                            unsigned short* __restrict__ WhTp, float* __restrict__ bcat) {
  int id = blockIdx.x * 256 + threadIdx.x;
  if (id < 65536) {                      // K3T[co*256+ci] = k3w[ci*256+co]
    K3h[id] = f2h(k3w[(id & 255) * 256 + (id >> 8)]);
    return;
  }
  id -= 65536;
  if (id < 409600) {                     // Wx2[dir][c<800][k<256]
    int dirv = id / 204800;
    int r = id % 204800;
    int c = r >> 8, k = r & 255;
    int u = c >> 2, q = c & 3;
    int g = q * 200 + u;
    const float* W = dirv ? Wb : Wf;
    Wx2[id] = f2h(W[k * 800 + g]);
    return;
  }
  id -= 409600;
  if (id < 372736) {                     // WhTp: [dir][m=4u+q][k]
    int dirv = id / 186368;
    int r = id % 186368;
    int m = r / 208, k = r % 208;
    int u = m >> 2, q = m & 3;
    float v = 0.f;
    if (u < 200 && k < 200) {
      const float* W = dirv ? Wb : Wf;
      v = W[(256 + k) * 800 + (q * 200 + u)];
    }
    WhTp[id] = f2h(v);
    return;
  }
  id -= 372736;
  if (id < 1600) {                       // bcat[dir*800 + c] with same perm
    int dirv = id / 800;
    int c = id % 800;
    int u = c >> 2, q = c & 3;
    bcat[id] = (dirv ? bbv : bfv)[q * 200 + u];
  }
}

// ---------------- conv2 via rank-1 collapse (6 FMA/elem)
__global__ void conv2_kernel(const float* __restrict__ s, const float* __restrict__ PQ,
                             unsigned short* __restrict__ C2) {
  int row = blockIdx.x;
  int co  = threadIdx.x;
  int t = row & (T_LEN - 1);
  float s0 = s[row];
  float sm = (t > 0)         ? s[row - 1] : 0.f;
  float sp = (t < T_LEN - 1) ? s[row + 1] : 0.f;
  const float* P = PQ;
  const float* Q = PQ + 768;
  float acc = 0.f;
  float a, m;
  a = fmaxf(sm, 0.f); m = fmaxf(-sm, 0.f);
  acc += a * P[0*256+co] + m * Q[0*256+co];
  a = fmaxf(s0, 0.f); m = fmaxf(-s0, 0.f);
  acc += a * P[1*256+co] + m * Q[1*256+co];
  a = fmaxf(sp, 0.f); m = fmaxf(-sp, 0.f);
  acc += a * P[2*256+co] + m * Q[2*256+co];
  C2[(size_t)row * 256 + co] = f2h(fmaxf(acc, 0.f));
}

// ---------------- MFMA GEMM, K=256 fixed. B given TRANSPOSED [n][256].
__global__ __launch_bounds__(256, 2) void gemm_kernel(
    const unsigned short* __restrict__ Ag, const unsigned short* __restrict__ Bg0,
    int N, int ntiles, int mode,
    unsigned short* __restrict__ Outp,
    const float* __restrict__ bias, const float* __restrict__ Sg,
    const float* __restrict__ k1aw, const float* __restrict__ k1ab,
    const int* __restrict__ lens, int t0)
{
  __shared__ __align__(16) unsigned short Bl[128*128];
  __shared__ __align__(16) unsigned short Al[128*40];
  __shared__ int rowsrc[128];
  int tid = threadIdx.x;
  int tm = blockIdx.x / ntiles, tn = blockIdx.x % ntiles;
  int col0 = tn * 128;
  int lane = tid & 63, wv = tid >> 6;
  int quad = lane >> 4, l16 = lane & 15;
  int wrow = (wv & 1) * 64, wcol = (wv >> 1) * 64;

  int dirv = 0;
  if (mode == 2) dirv = ((tm * 128) >> 8) >> 5;
  const unsigned short* Bg = Bg0 + (size_t)dirv * 204800;

  if (tid < 128) {
    int r;
    if (mode == 2) {
      int m = tm * 128 + tid;
      int ch = m >> 8;
      int ls = m & 255;
      int b = ch & 31, dd = ch >> 5;
      int L = lens[b]; L = (L < 0) ? 0 : ((L > T_LEN) ? T_LEN : L);
      int t = t0 + ls;
      int src = dd ? (L - 1 - t) : t;
      src = (src < 0) ? 0 : ((src > T_LEN - 1) ? (T_LEN - 1) : src);
      r = b * T_LEN + src;
    } else {
      r = tm * 128 + tid;
    }
    rowsrc[tid] = r;
  }

  floatx4 acc[16];
  #pragma unroll
  for (int i = 0; i < 16; ++i) acc[i] = (floatx4){0.f,0.f,0.f,0.f};

  for (int ph = 0; ph < 2; ++ph) {
    __syncthreads();
    #pragma unroll
    for (int it = 0; it < 8; ++it) {
      int idx = it * 256 + tid;
      int n  = idx >> 4;
      int k8 = idx & 15;
      int nn = col0 + n;
      uint4 v = (uint4){0u,0u,0u,0u};
      if (nn < N) v = *(const uint4*)(Bg + (size_t)nn * 256 + ph * 128 + k8 * 8);
      *(uint4*)(&Bl[n * 128 + ((k8 ^ (n & 7)) * 8)]) = v;
    }
    for (int kb2 = 0; kb2 < 4; ++kb2) {
      int kb = ph * 4 + kb2;
      __syncthreads();
      #pragma unroll
      for (int i = 0; i < 2; ++i) {
        int c2 = i * 256 + tid;
        int r = c2 >> 2, kc = (c2 & 3) * 8;
        uint4 v = *(const uint4*)(Ag + (size_t)rowsrc[r] * 256 + kb * 32 + kc);
        *(uint4*)(&Al[r * 40 + kc]) = v;
      }
      __syncthreads();
      f16x8 af[4], bfr[4];
      #pragma unroll
      for (int mt = 0; mt < 4; ++mt)
        af[mt] = *(const f16x8*)(&Al[(wrow + mt*16 + l16) * 40 + quad * 8]);
      #pragma unroll
      for (int nt = 0; nt < 4; ++nt) {
        int nl = wcol + nt*16 + l16;
        int c = kb2 * 4 + quad;
        bfr[nt] = *(const f16x8*)(&Bl[nl * 128 + ((c ^ (nl & 7)) * 8)]);
      }
      #pragma unroll
      for (int mt = 0; mt < 4; ++mt)
        #pragma unroll
        for (int nt = 0; nt < 4; ++nt)
          acc[mt*4+nt] = __builtin_amdgcn_mfma_f32_16x16x32_f16(af[mt], bfr[nt], acc[mt*4+nt], 0, 0, 0);
    }
  }
  #pragma unroll
  for (int mt = 0; mt < 4; ++mt) {
    #pragma unroll
    for (int nt = 0; nt < 4; ++nt) {
      floatx4 v = acc[mt*4+nt];
      int col = col0 + wcol + nt*16 + l16;
      if (col < N) {
        #pragma unroll
        for (int r = 0; r < 4; ++r) {
          int row = tm * 128 + wrow + mt*16 + quad*4 + r;
          float x = v[r];
          float o;
          if (mode == 0) {
            float sv = Sg[row];
            float a1 = sv * k1aw[col] + k1ab[col];
            o = fmaxf(x, 0.f) + fmaxf(a1, 0.f);
          } else {
            o = x + bias[dirv * 800 + col];
          }
          Outp[(size_t)row * N + col] = f2h(o);
        }
      }
    }
  }
}

// ---------------- MFMA-batched recurrent LSTM: 4 WGs, 16 chains each.
// z^T[m=4u+q][n=chain] = WhTp[m][k] * hB[k][n]; weights persistent in regs
// (182/lane, AGPR-friendly: mfma reads AGPRs directly). All 4 gates of unit u
// land in one lane's 4 acc regs -> in-lane activation, c-state in 7 VGPRs.
__global__ __launch_bounds__(512) void lstm_kernel(
    const unsigned short* __restrict__ XWbuf,  // [64][TB][800] f16, cols c=4u+q, bias folded
    const unsigned short* __restrict__ WhTp,   // [dir][896][208] f16
    const int* __restrict__ lens,
    unsigned short* __restrict__ fwH, unsigned short* __restrict__ bwH,
    float* __restrict__ cState, unsigned short* __restrict__ hState,
    int t0)
{
  int wg  = blockIdx.x;          // 0..3
  int dir = wg >> 1;
  int ch0 = dir * 32 + (wg & 1) * 16;
  int tid = threadIdx.x;
  int w    = tid >> 6;
  int quad = (tid >> 4) & 3;
  int l16  = tid & 15;
  int ch = ch0 + l16;
  int b  = ch & 31;

  __shared__ __align__(16) unsigned short hB[2][16][232];
  __shared__ int Lsh[16];

  if (tid < 16) {
    int L = lens[(ch0 + tid) & 31];
    L = (L < 0) ? 0 : ((L > T_LEN) ? T_LEN : L);
    Lsh[tid] = L;
  }
  __syncthreads();
  int Llane = Lsh[l16];
  int maxL = 0;
  #pragma unroll
  for (int j = 0; j < 16; ++j) maxL = max(maxL, Lsh[j]);
  int tend = t0 + TB; if (tend > maxL) tend = maxL;

  // init h panel for this chunk
  for (int r = tid; r < 16 * 224; r += 512) {
    int cl = r / 224, u = r % 224;
    unsigned short hv = 0;
    if (t0 > 0) hv = hState[(ch0 + cl) * 224 + u];
    hB[0][cl][u] = hv;
  }

  // persistent weight fragments: A[i][kt], m=(w*7+i)*16+l16, k=kt*16+quad*4
  f16x4 A[7][13];
  {
    const unsigned short* Wbase = WhTp + (size_t)dir * 896 * 208;
    #pragma unroll
    for (int i = 0; i < 7; ++i) {
      const unsigned short* rp = Wbase + (size_t)((w * 7 + i) * 16 + l16) * 208 + quad * 4;
      #pragma unroll
      for (int kt = 0; kt < 13; ++kt)
        A[i][kt] = *(const f16x4*)(rp + kt * 16);
    }
  }

  float c[7];
  #pragma unroll
  for (int i = 0; i < 7; ++i) {
    int u = w * 28 + i * 4 + quad;
    c[i] = (t0 > 0) ? cState[ch * 224 + u] : 0.f;
  }

  const unsigned short* XWl = XWbuf + (size_t)ch * TB * 800;
  uint2 xw[7];
  #pragma unroll
  for (int i = 0; i < 7; ++i) {
    int u = w * 28 + i * 4 + quad;
    xw[i] = *(const uint2*)(XWl + 4 * u);
  }

  unsigned short* Hd = dir ? bwH : fwH;
  int pb = 0;
  __syncthreads();

  for (int t = t0; t < tend; ++t) {
    int tl = t - t0;
    f16x4 Bf[13];
    #pragma unroll
    for (int kt = 0; kt < 13; ++kt)
      Bf[kt] = *(const f16x4*)&hB[pb][l16][kt * 16 + quad * 4];
    int tln = (t + 1 < tend) ? (tl + 1) : tl;
    #pragma unroll
    for (int i = 0; i < 7; ++i) {
      int u = w * 28 + i * 4 + quad;
      floatx4 acc;
      {
        f16x2 lo = __builtin_bit_cast(f16x2, xw[i].x);
        f16x2 hi = __builtin_bit_cast(f16x2, xw[i].y);
        acc[0] = (float)lo[0]; acc[1] = (float)lo[1];
        acc[2] = (float)hi[0]; acc[3] = (float)hi[1];
      }
      // prefetch next step's xw (consumed after next barrier)
      xw[i] = *(const uint2*)(XWl + (size_t)tln * 800 + 4 * u);
      #pragma unroll
      for (int kt = 0; kt < 13; ++kt)
        acc = __builtin_amdgcn_mfma_f32_16x16x16f16(A[i][kt], Bf[kt], acc, 0, 0, 0);
      float zi = acc[0], zj = acc[1], zf = acc[2], zo = acc[3];
      c[i] = c[i] * sigm(zf + 1.f) + sigm(zi) * tanh_fast(zj);
      float h = tanh_fast(c[i]) * sigm(zo);
      unsigned short hh = f2h(h);
      hB[pb ^ 1][l16][u] = hh;
      if (u < 200 && t < Llane) {
        int row = dir ? (b * T_LEN + (Llane - 1 - t)) : (b * T_LEN + t);
        Hd[(size_t)row * HH + u] = hh;
      }
    }
    pb ^= 1;
    __syncthreads();
  }

  // save state for next chunk
  #pragma unroll
  for (int i = 0; i < 7; ++i) {
    int u = w * 28 + i * 4 + quad;
    cState[ch * 224 + u] = c[i];
  }
  for (int r = tid; r < 16 * 224; r += 512) {
    int cl = r / 224, u = r % 224;
    hState[(ch0 + cl) * 224 + u] = hB[pb][cl][u];
  }
}

// ---------------- logits = [fwH|bwH] @ Wd + bd
__global__ __launch_bounds__(256) void out_kernel(
    const unsigned short* __restrict__ fwH, const unsigned short* __restrict__ bwH,
    const float* __restrict__ Wd, const float* __restrict__ bd, float* __restrict__ out)
{
  __shared__ float wd[2000];
  int tid = threadIdx.x;
  for (int i = tid; i < 2000; i += 256) wd[i] = Wd[i];
  __syncthreads();
  int row = blockIdx.x * 256 + tid;
  float acc0 = bd[0], acc1 = bd[1], acc2 = bd[2], acc3 = bd[3], acc4 = bd[4];
  const unsigned int* fu = (const unsigned int*)(fwH + (size_t)row * HH);
  const unsigned int* bu = (const unsigned int*)(bwH + (size_t)row * HH);
  #pragma unroll 4
  for (int i = 0; i < 100; ++i) {
    f16x2 pf = __builtin_bit_cast(f16x2, fu[i]);
    f16x2 pb = __builtin_bit_cast(f16x2, bu[i]);
    int k = 2 * i;
    float f0 = (float)pf[0], f1 = (float)pf[1];
    float b0 = (float)pb[0], b1 = (float)pb[1];
    const float* w0 = &wd[k*5];
    const float* w1 = &wd[(k+1)*5];
    const float* w2 = &wd[(200+k)*5];
    const float* w3 = &wd[(201+k)*5];
    acc0 += f0*w0[0] + f1*w1[0] + b0*w2[0] + b1*w3[0];
    acc1 += f0*w0[1] + f1*w1[1] + b0*w2[1] + b1*w3[1];
    acc2 += f0*w0[2] + f1*w1[2] + b0*w2[2] + b1*w3[2];
    acc3 += f0*w0[3] + f1*w1[3] + b0*w2[3] + b1*w3[3];
    acc4 += f0*w0[4] + f1*w1[4] + b0*w2[4] + b1*w3[4];
  }
  float* o = out + (size_t)row * 5;
  o[0]=acc0; o[1]=acc1; o[2]=acc2; o[3]=acc3; o[4]=acc4;
}

extern "C" void kernel_launch(void* const* d_in, const int* in_sizes, int n_in,
                              void* d_out, int out_size, void* d_ws, size_t ws_size,
                              hipStream_t stream)
{
  const float* signals = (const float*)d_in[0];
  const int*   lens    = (const int*)  d_in[1];
  const float* k1w     = (const float*)d_in[2];
  const float* k1aw    = (const float*)d_in[3];
  const float* k1ab    = (const float*)d_in[4];
  const float* k2w     = (const float*)d_in[5];
  const float* k3w     = (const float*)d_in[6];
  const float* Wf      = (const float*)d_in[7];
  const float* bf      = (const float*)d_in[8];
  const float* Wb      = (const float*)d_in[9];
  const float* bb      = (const float*)d_in[10];
  const float* Wd      = (const float*)d_in[11];
  const float* bd      = (const float*)d_in[12];
  float* out = (float*)d_out;
  char* ws = (char*)d_ws;

  size_t szC2   = (size_t)NROWS * 256 * 2;
  size_t szXWb  = (size_t)64 * TB * 800 * 2;
  size_t szA    = (szC2 > szXWb) ? szC2 : szXWb;
  size_t oA    = 0;
  size_t oE    = oA    + szA;
  size_t oFw   = oE    + (size_t)NROWS*256*2;
  size_t oBw   = oFw   + (size_t)NROWS*HH*2;
  size_t oWhT  = oBw   + (size_t)NROWS*HH*2;
  size_t oWx2  = oWhT  + (size_t)2*896*208*2;
  size_t oK3   = oWx2  + (size_t)2*256*800*2;
  size_t oPQ   = oK3   + (size_t)256*256*2;
  size_t oBc   = oPQ   + 1536*4;
  size_t oCst  = oBc   + 1600*4;
  size_t oHst  = oCst  + (size_t)64*224*4;
  size_t total = oHst  + (size_t)64*224*2;          // ~121 MB
  if (ws_size < total) return;

  unsigned short* C2    = (unsigned short*)(ws + oA);
  unsigned short* XWbuf = (unsigned short*)(ws + oA);
  unsigned short* E     = (unsigned short*)(ws + oE);
  unsigned short* fwH   = (unsigned short*)(ws + oFw);
  unsigned short* bwH   = (unsigned short*)(ws + oBw);
  unsigned short* WhTp  = (unsigned short*)(ws + oWhT);
  unsigned short* Wx2   = (unsigned short*)(ws + oWx2);
  unsigned short* K3h   = (unsigned short*)(ws + oK3);
  float* PQ     = (float*)(ws + oPQ);
  float* bcat   = (float*)(ws + oBc);
  float* cState = (float*)(ws + oCst);
  unsigned short* hState = (unsigned short*)(ws + oHst);

  hipMemsetAsync(fwH, 0, (size_t)2*NROWS*HH*2, stream);
  pq_kernel  <<<6,     256, 0, stream>>>(k1w, k2w, PQ);
  prep_kernel<<<3319,  256, 0, stream>>>(k3w, Wf, bf, Wb, bb, K3h, Wx2, WhTp, bcat);
  conv2_kernel<<<NROWS, 256, 0, stream>>>(signals, PQ, C2);
  gemm_kernel<<<1024,  256, 0, stream>>>(C2, K3h, 256, 2, 0, E, nullptr, signals, k1aw, k1ab, nullptr, 0);
  for (int t0 = 0; t0 < T_LEN; t0 += TB) {
    gemm_kernel<<<896, 256, 0, stream>>>(E, Wx2, 800, 7, 2, XWbuf, bcat, nullptr, nullptr, nullptr, lens, t0);
    lstm_kernel<<<4,   512, 0, stream>>>(XWbuf, WhTp, lens, fwH, bwH, cState, hState, t0);
  }
  out_kernel <<<256,   256, 0, stream>>>(fwH, bwH, Wd, bd, out);
}

// Round 8
// 8249.348 us; speedup vs baseline: 1.0020x; 1.0020x over previous
//
#include <hip/hip_runtime.h>
#include <cstdint>

#define T_LEN 2048
#define NB    32
#define NROWS (NB*T_LEN)   // 65536
#define HH    200
#define TB    256          // LSTM time-chunk (per dispatch)

typedef _Float16 f16;
typedef _Float16 f16x2 __attribute__((ext_vector_type(2)));
typedef _Float16 f16x4 __attribute__((ext_vector_type(4)));
typedef _Float16 f16x8 __attribute__((ext_vector_type(8)));
typedef float   floatx4 __attribute__((ext_vector_type(4)));

static __device__ __forceinline__ unsigned short f2h(float x) {
  f16 h = (f16)x; return __builtin_bit_cast(unsigned short, h);
}
static __device__ __forceinline__ float sigm(float x) {
  return __builtin_amdgcn_rcpf(1.f + __expf(-x));
}
static __device__ __forceinline__ float tanh_fast(float x) {
  return 1.f - 2.f * __builtin_amdgcn_rcpf(__expf(2.f * x) + 1.f);
}

// ---------------- P/Q precompute: P[dt,co]=sum_ci relu(k1)k2, Q with relu(-k1)
__global__ void pq_kernel(const float* __restrict__ k1w, const float* __restrict__ k2w,
                          float* __restrict__ PQ) {
  int id = blockIdx.x * 256 + threadIdx.x;   // 1536 total
  int pq = id / 768;
  int rem = id % 768;
  int wdt = rem / 256;
  int co  = rem % 256;
  float acc = 0.f;
  for (int ci = 0; ci < 256; ++ci) {
    float k = k1w[ci];
    float kk = pq ? fmaxf(-k, 0.f) : fmaxf(k, 0.f);
    acc += kk * k2w[((size_t)wdt * 256 + ci) * 256 + co];
  }
  PQ[id] = acc;
}

// ---------------- f16 weight prep
// K3T[co][ci] ; Wx2[dir][c][k] with permuted col c=4u+q (gate g=q*200+u) ;
// WhTp[dir][m<896][k<208], row m=4u+q -> Wh[k][q*200+u], zero-padded ; bcat permuted.
__global__ void prep_kernel(const float* __restrict__ k3w,
                            const float* __restrict__ Wf, const float* __restrict__ bfv,
                            const float* __restrict__ Wb, const float* __restrict__ bbv,
                            unsigned short* __restrict__ K3h, unsigned short* __restrict__ Wx2,
                            unsigned short* __restrict__ WhTp, float* __restrict__ bcat) {
  int id = blockIdx.x * 256 + threadIdx.x;
  if (id < 65536) {                      // K3T[co*256+ci] = k3w[ci*256+co]
    K3h[id] = f2h(k3w[(id & 255) * 256 + (id >> 8)]);
    return;
  }
  id -= 65536;
  if (id < 409600) {                     // Wx2[dir][c<800][k<256]
    int dirv = id / 204800;
    int r = id % 204800;
    int c = r >> 8, k = r & 255;
    int u = c >> 2, q = c & 3;
    int g = q * 200 + u;
    const float* W = dirv ? Wb : Wf;
    Wx2[id] = f2h(W[k * 800 + g]);
    return;
  }
  id -= 409600;
  if (id < 372736) {                     // WhTp: [dir][m=4u+q][k<208]
    int dirv = id / 186368;
    int r = id % 186368;
    int m = r / 208, k = r % 208;
    int u = m >> 2, q = m & 3;
    float v = 0.f;
    if (u < 200 && k < 200) {
      const float* W = dirv ? Wb : Wf;
      v = W[(256 + k) * 800 + (q * 200 + u)];
    }
    WhTp[id] = f2h(v);
    return;
  }
  id -= 372736;
  if (id < 1600) {                       // bcat[dir*800 + c] with same perm
    int dirv = id / 800;
    int c = id % 800;
    int u = c >> 2, q = c & 3;
    bcat[id] = (dirv ? bbv : bfv)[q * 200 + u];
  }
}

// ---------------- conv2 via rank-1 collapse (6 FMA/elem)
__global__ void conv2_kernel(const float* __restrict__ s, const float* __restrict__ PQ,
                             unsigned short* __restrict__ C2) {
  int row = blockIdx.x;
  int co  = threadIdx.x;
  int t = row & (T_LEN - 1);
  float s0 = s[row];
  float sm = (t > 0)         ? s[row - 1] : 0.f;
  float sp = (t < T_LEN - 1) ? s[row + 1] : 0.f;
  const float* P = PQ;
  const float* Q = PQ + 768;
  float acc = 0.f;
  float a, m;
  a = fmaxf(sm, 0.f); m = fmaxf(-sm, 0.f);
  acc += a * P[0*256+co] + m * Q[0*256+co];
  a = fmaxf(s0, 0.f); m = fmaxf(-s0, 0.f);
  acc += a * P[1*256+co] + m * Q[1*256+co];
  a = fmaxf(sp, 0.f); m = fmaxf(-sp, 0.f);
  acc += a * P[2*256+co] + m * Q[2*256+co];
  C2[(size_t)row * 256 + co] = f2h(fmaxf(acc, 0.f));
}

// ---------------- MFMA GEMM, K=256 fixed. B given TRANSPOSED [n][256].
__global__ __launch_bounds__(256, 2) void gemm_kernel(
    const unsigned short* __restrict__ Ag, const unsigned short* __restrict__ Bg0,
    int N, int ntiles, int mode,
    unsigned short* __restrict__ Outp,
    const float* __restrict__ bias, const float* __restrict__ Sg,
    const float* __restrict__ k1aw, const float* __restrict__ k1ab,
    const int* __restrict__ lens, int t0)
{
  __shared__ __align__(16) unsigned short Bl[128*128];
  __shared__ __align__(16) unsigned short Al[128*40];
  __shared__ int rowsrc[128];
  int tid = threadIdx.x;
  int tm = blockIdx.x / ntiles, tn = blockIdx.x % ntiles;
  int col0 = tn * 128;
  int lane = tid & 63, wv = tid >> 6;
  int quad = lane >> 4, l16 = lane & 15;
  int wrow = (wv & 1) * 64, wcol = (wv >> 1) * 64;

  int dirv = 0;
  if (mode == 2) dirv = ((tm * 128) >> 8) >> 5;
  const unsigned short* Bg = Bg0 + (size_t)dirv * 204800;

  if (tid < 128) {
    int r;
    if (mode == 2) {
      int m = tm * 128 + tid;
      int ch = m >> 8;
      int ls = m & 255;
      int b = ch & 31, dd = ch >> 5;
      int L = lens[b]; L = (L < 0) ? 0 : ((L > T_LEN) ? T_LEN : L);
      int t = t0 + ls;
      int src = dd ? (L - 1 - t) : t;
      src = (src < 0) ? 0 : ((src > T_LEN - 1) ? (T_LEN - 1) : src);
      r = b * T_LEN + src;
    } else {
      r = tm * 128 + tid;
    }
    rowsrc[tid] = r;
  }

  floatx4 acc[16];
  #pragma unroll
  for (int i = 0; i < 16; ++i) acc[i] = (floatx4){0.f,0.f,0.f,0.f};

  for (int ph = 0; ph < 2; ++ph) {
    __syncthreads();
    #pragma unroll
    for (int it = 0; it < 8; ++it) {
      int idx = it * 256 + tid;
      int n  = idx >> 4;
      int k8 = idx & 15;
      int nn = col0 + n;
      uint4 v = (uint4){0u,0u,0u,0u};
      if (nn < N) v = *(const uint4*)(Bg + (size_t)nn * 256 + ph * 128 + k8 * 8);
      *(uint4*)(&Bl[n * 128 + ((k8 ^ (n & 7)) * 8)]) = v;
    }
    for (int kb2 = 0; kb2 < 4; ++kb2) {
      int kb = ph * 4 + kb2;
      __syncthreads();
      #pragma unroll
      for (int i = 0; i < 2; ++i) {
        int c2 = i * 256 + tid;
        int r = c2 >> 2, kc = (c2 & 3) * 8;
        uint4 v = *(const uint4*)(Ag + (size_t)rowsrc[r] * 256 + kb * 32 + kc);
        *(uint4*)(&Al[r * 40 + kc]) = v;
      }
      __syncthreads();
      f16x8 af[4], bfr[4];
      #pragma unroll
      for (int mt = 0; mt < 4; ++mt)
        af[mt] = *(const f16x8*)(&Al[(wrow + mt*16 + l16) * 40 + quad * 8]);
      #pragma unroll
      for (int nt = 0; nt < 4; ++nt) {
        int nl = wcol + nt*16 + l16;
        int c = kb2 * 4 + quad;
        bfr[nt] = *(const f16x8*)(&Bl[nl * 128 + ((c ^ (nl & 7)) * 8)]);
      }
      #pragma unroll
      for (int mt = 0; mt < 4; ++mt)
        #pragma unroll
        for (int nt = 0; nt < 4; ++nt)
          acc[mt*4+nt] = __builtin_amdgcn_mfma_f32_16x16x32_f16(af[mt], bfr[nt], acc[mt*4+nt], 0, 0, 0);
    }
  }
  #pragma unroll
  for (int mt = 0; mt < 4; ++mt) {
    #pragma unroll
    for (int nt = 0; nt < 4; ++nt) {
      floatx4 v = acc[mt*4+nt];
      int col = col0 + wcol + nt*16 + l16;
      if (col < N) {
        #pragma unroll
        for (int r = 0; r < 4; ++r) {
          int row = tm * 128 + wrow + mt*16 + quad*4 + r;
          float x = v[r];
          float o;
          if (mode == 0) {
            float sv = Sg[row];
            float a1 = sv * k1aw[col] + k1ab[col];
            o = fmaxf(x, 0.f) + fmaxf(a1, 0.f);
          } else {
            o = x + bias[dirv * 800 + col];
          }
          Outp[(size_t)row * N + col] = f2h(o);
        }
      }
    }
  }
}

// ---------------- MFMA-batched recurrent LSTM: 4 WGs, 16 chains each.
// ROUND-5 BODY VERBATIM (passed, absmax 0.0039) + ONE change:
// amdgpu_waves_per_eu(2,2) -> 256-reg budget so A[7][13] (182 regs) stays in
// the unified VGPR/AGPR file instead of spilling to scratch (r5: VGPR=128,
// 4010 cyc/step latency-bound on scratch reloads).
__global__ __launch_bounds__(512) __attribute__((amdgpu_waves_per_eu(2, 2)))
void lstm_kernel(
    const unsigned short* __restrict__ XWbuf,  // [64][TB][800] f16, cols c=4u+q, bias folded
    const unsigned short* __restrict__ WhTp,   // [dir][896][208] f16
    const int* __restrict__ lens,
    unsigned short* __restrict__ fwH, unsigned short* __restrict__ bwH,
    float* __restrict__ cState, unsigned short* __restrict__ hState,
    int t0)
{
  int wg  = blockIdx.x;          // 0..3
  int dir = wg >> 1;
  int ch0 = dir * 32 + (wg & 1) * 16;
  int tid = threadIdx.x;
  int w    = tid >> 6;
  int quad = (tid >> 4) & 3;
  int l16  = tid & 15;
  int ch = ch0 + l16;
  int b  = ch & 31;

  __shared__ __align__(16) unsigned short hB[2][16][232];
  __shared__ int Lsh[16];

  if (tid < 16) {
    int L = lens[(ch0 + tid) & 31];
    L = (L < 0) ? 0 : ((L > T_LEN) ? T_LEN : L);
    Lsh[tid] = L;
  }
  __syncthreads();
  int Llane = Lsh[l16];
  int maxL = 0;
  #pragma unroll
  for (int j = 0; j < 16; ++j) maxL = max(maxL, Lsh[j]);
  int tend = t0 + TB; if (tend > maxL) tend = maxL;

  // init h panel for this chunk
  for (int r = tid; r < 16 * 224; r += 512) {
    int cl = r / 224, u = r % 224;
    unsigned short hv = 0;
    if (t0 > 0) hv = hState[(ch0 + cl) * 224 + u];
    hB[0][cl][u] = hv;
  }

  // persistent weight fragments: A[i][kt], m=(w*7+i)*16+l16, k=kt*16+quad*4
  f16x4 A[7][13];
  {
    const unsigned short* Wbase = WhTp + (size_t)dir * 896 * 208;
    #pragma unroll
    for (int i = 0; i < 7; ++i) {
      const unsigned short* rp = Wbase + (size_t)((w * 7 + i) * 16 + l16) * 208 + quad * 4;
      #pragma unroll
      for (int kt = 0; kt < 13; ++kt)
        A[i][kt] = *(const f16x4*)(rp + kt * 16);
    }
  }

  float c[7];
  #pragma unroll
  for (int i = 0; i < 7; ++i) {
    int u = w * 28 + i * 4 + quad;
    c[i] = (t0 > 0) ? cState[ch * 224 + u] : 0.f;
  }

  const unsigned short* XWl = XWbuf + (size_t)ch * TB * 800;
  uint2 xw[7];
  #pragma unroll
  for (int i = 0; i < 7; ++i) {
    int u = w * 28 + i * 4 + quad;
    xw[i] = *(const uint2*)(XWl + 4 * u);
  }

  unsigned short* Hd = dir ? bwH : fwH;
  int pb = 0;
  __syncthreads();

  for (int t = t0; t < tend; ++t) {
    int tl = t - t0;
    f16x4 Bf[13];
    #pragma unroll
    for (int kt = 0; kt < 13; ++kt)
      Bf[kt] = *(const f16x4*)&hB[pb][l16][kt * 16 + quad * 4];
    int tln = (t + 1 < tend) ? (tl + 1) : tl;
    #pragma unroll
    for (int i = 0; i < 7; ++i) {
      int u = w * 28 + i * 4 + quad;
      floatx4 acc;
      {
        f16x2 lo = __builtin_bit_cast(f16x2, xw[i].x);
        f16x2 hi = __builtin_bit_cast(f16x2, xw[i].y);
        acc[0] = (float)lo[0]; acc[1] = (float)lo[1];
        acc[2] = (float)hi[0]; acc[3] = (float)hi[1];
      }
      // prefetch next step's xw (consumed after next barrier)
      xw[i] = *(const uint2*)(XWl + (size_t)tln * 800 + 4 * u);
      #pragma unroll
      for (int kt = 0; kt < 13; ++kt)
        acc = __builtin_amdgcn_mfma_f32_16x16x16f16(A[i][kt], Bf[kt], acc, 0, 0, 0);
      float zi = acc[0], zj = acc[1], zf = acc[2], zo = acc[3];
      c[i] = c[i] * sigm(zf + 1.f) + sigm(zi) * tanh_fast(zj);
      float h = tanh_fast(c[i]) * sigm(zo);
      unsigned short hh = f2h(h);
      hB[pb ^ 1][l16][u] = hh;
      if (u < 200 && t < Llane) {
        int row = dir ? (b * T_LEN + (Llane - 1 - t)) : (b * T_LEN + t);
        Hd[(size_t)row * HH + u] = hh;
      }
    }
    pb ^= 1;
    __syncthreads();
  }

  // save state for next chunk
  #pragma unroll
  for (int i = 0; i < 7; ++i) {
    int u = w * 28 + i * 4 + quad;
    cState[ch * 224 + u] = c[i];
  }
  for (int r = tid; r < 16 * 224; r += 512) {
    int cl = r / 224, u = r % 224;
    hState[(ch0 + cl) * 224 + u] = hB[pb][cl][u];
  }
}

// ---------------- logits = [fwH|bwH] @ Wd + bd
__global__ __launch_bounds__(256) void out_kernel(
    const unsigned short* __restrict__ fwH, const unsigned short* __restrict__ bwH,
    const float* __restrict__ Wd, const float* __restrict__ bd, float* __restrict__ out)
{
  __shared__ float wd[2000];
  int tid = threadIdx.x;
  for (int i = tid; i < 2000; i += 256) wd[i] = Wd[i];
  __syncthreads();
  int row = blockIdx.x * 256 + tid;
  float acc0 = bd[0], acc1 = bd[1], acc2 = bd[2], acc3 = bd[3], acc4 = bd[4];
  const unsigned int* fu = (const unsigned int*)(fwH + (size_t)row * HH);
  const unsigned int* bu = (const unsigned int*)(bwH + (size_t)row * HH);
  #pragma unroll 4
  for (int i = 0; i < 100; ++i) {
    f16x2 pf = __builtin_bit_cast(f16x2, fu[i]);
    f16x2 pb = __builtin_bit_cast(f16x2, bu[i]);
    int k = 2 * i;
    float f0 = (float)pf[0], f1 = (float)pf[1];
    float b0 = (float)pb[0], b1 = (float)pb[1];
    const float* w0 = &wd[k*5];
    const float* w1 = &wd[(k+1)*5];
    const float* w2 = &wd[(200+k)*5];
    const float* w3 = &wd[(201+k)*5];
    acc0 += f0*w0[0] + f1*w1[0] + b0*w2[0] + b1*w3[0];
    acc1 += f0*w0[1] + f1*w1[1] + b0*w2[1] + b1*w3[1];
    acc2 += f0*w0[2] + f1*w1[2] + b0*w2[2] + b1*w3[2];
    acc3 += f0*w0[3] + f1*w1[3] + b0*w2[3] + b1*w3[3];
    acc4 += f0*w0[4] + f1*w1[4] + b0*w2[4] + b1*w3[4];
  }
  float* o = out + (size_t)row * 5;
  o[0]=acc0; o[1]=acc1; o[2]=acc2; o[3]=acc3; o[4]=acc4;
}

extern "C" void kernel_launch(void* const* d_in, const int* in_sizes, int n_in,
                              void* d_out, int out_size, void* d_ws, size_t ws_size,
                              hipStream_t stream)
{
  const float* signals = (const float*)d_in[0];
  const int*   lens    = (const int*)  d_in[1];
  const float* k1w     = (const float*)d_in[2];
  const float* k1aw    = (const float*)d_in[3];
  const float* k1ab    = (const float*)d_in[4];
  const float* k2w     = (const float*)d_in[5];
  const float* k3w     = (const float*)d_in[6];
  const float* Wf      = (const float*)d_in[7];
  const float* bf      = (const float*)d_in[8];
  const float* Wb      = (const float*)d_in[9];
  const float* bb      = (const float*)d_in[10];
  const float* Wd      = (const float*)d_in[11];
  const float* bd      = (const float*)d_in[12];
  float* out = (float*)d_out;
  char* ws = (char*)d_ws;

  size_t szC2   = (size_t)NROWS * 256 * 2;
  size_t szXWb  = (size_t)64 * TB * 800 * 2;
  size_t szA    = (szC2 > szXWb) ? szC2 : szXWb;
  size_t oA    = 0;
  size_t oE    = oA    + szA;
  size_t oFw   = oE    + (size_t)NROWS*256*2;
  size_t oBw   = oFw   + (size_t)NROWS*HH*2;
  size_t oWhT  = oBw   + (size_t)NROWS*HH*2;
  size_t oWx2  = oWhT  + (size_t)2*896*208*2;
  size_t oK3   = oWx2  + (size_t)2*256*800*2;
  size_t oPQ   = oK3   + (size_t)256*256*2;
  size_t oBc   = oPQ   + 1536*4;
  size_t oCst  = oBc   + 1600*4;
  size_t oHst  = oCst  + (size_t)64*224*4;
  size_t total = oHst  + (size_t)64*224*2;          // ~121 MB
  if (ws_size < total) return;

  unsigned short* C2    = (unsigned short*)(ws + oA);
  unsigned short* XWbuf = (unsigned short*)(ws + oA);
  unsigned short* E     = (unsigned short*)(ws + oE);
  unsigned short* fwH   = (unsigned short*)(ws + oFw);
  unsigned short* bwH   = (unsigned short*)(ws + oBw);
  unsigned short* WhTp  = (unsigned short*)(ws + oWhT);
  unsigned short* Wx2   = (unsigned short*)(ws + oWx2);
  unsigned short* K3h   = (unsigned short*)(ws + oK3);
  float* PQ     = (float*)(ws + oPQ);
  float* bcat   = (float*)(ws + oBc);
  float* cState = (float*)(ws + oCst);
  unsigned short* hState = (unsigned short*)(ws + oHst);

  hipMemsetAsync(fwH, 0, (size_t)2*NROWS*HH*2, stream);
  pq_kernel  <<<6,     256, 0, stream>>>(k1w, k2w, PQ);
  prep_kernel<<<3319,  256, 0, stream>>>(k3w, Wf, bf, Wb, bb, K3h, Wx2, WhTp, bcat);
  conv2_kernel<<<NROWS, 256, 0, stream>>>(signals, PQ, C2);
  gemm_kernel<<<1024,  256, 0, stream>>>(C2, K3h, 256, 2, 0, E, nullptr, signals, k1aw, k1ab, nullptr, 0);
  for (int t0 = 0; t0 < T_LEN; t0 += TB) {
    gemm_kernel<<<896, 256, 0, stream>>>(E, Wx2, 800, 7, 2, XWbuf, bcat, nullptr, nullptr, nullptr, lens, t0);
    lstm_kernel<<<4,   512, 0, stream>>>(XWbuf, WhTp, lens, fwH, bwH, cState, hState, t0);
  }
  out_kernel <<<256,   256, 0, stream>>>(fwH, bwH, Wd, bd, out);
}